// Round 1
// baseline (66.793 us; speedup 1.0000x reference)
//
#include <hip/hip_runtime.h>

#define NF 256      // NUM_NEURONS
#define NT 68       // extended knot count: 64 - 2 + 2*3

// Extended knot vector, matching numpy construction:
// left pads [-0.0035,-0.003,-0.0025], base = [-0.002,-0.0015,-0.001] ++
// linspace(0,1,56) ++ [1.001,1.0015,1.002], right pads [1.0025,1.003,1.0035].
__device__ __forceinline__ float knotf(int idx) {
    if (idx <= 5) return -0.0035f + 0.0005f * (float)idx;     // t[0..5]
    if (idx >= 62) return 1.001f + 0.0005f * (float)(idx - 62); // t[62..67]
    int j = idx - 6;                                           // 0..55
    if (j == 55) return 1.0f;                                  // linspace endpoint exact
    return (float)((double)j * (1.0 / 55.0));                  // numpy linspace: j*step
}

__global__ __launch_bounds__(256) void bspline_kernel(
    const float* __restrict__ x,
    const float* __restrict__ cp,     // (64, 256) row-major
    const float* __restrict__ bias,   // (256,)
    float* __restrict__ out,
    int total4)
{
    __shared__ float t[NT];
    // reciprocal knot-difference tables per interval i in [6,60]
    __shared__ float rd11[61], rd21[61], rd22[61], rd31[61], rd32[61], rd33[61];

    const int tid = threadIdx.x;
    if (tid < NT) t[tid] = knotf(tid);
    __syncthreads();
    if (tid >= 6 && tid <= 60) {
        rd11[tid] = 1.0f / (t[tid + 1] - t[tid]);
        rd21[tid] = 1.0f / (t[tid + 1] - t[tid - 1]);
        rd22[tid] = 1.0f / (t[tid + 2] - t[tid]);
        rd31[tid] = 1.0f / (t[tid + 1] - t[tid - 2]);
        rd32[tid] = 1.0f / (t[tid + 2] - t[tid - 1]);
        rd33[tid] = 1.0f / (t[tid + 3] - t[tid]);
    }
    __syncthreads();

    const int gid = blockIdx.x * blockDim.x + tid;
    if (gid >= total4) return;

    const float4 xv = reinterpret_cast<const float4*>(x)[gid];
    const int f0 = (gid * 4) & (NF - 1);   // feature index of lane 0 (multiple of 4)
    const float4 bv = reinterpret_cast<const float4*>(bias)[f0 >> 2];

    float xs[4] = {xv.x, xv.y, xv.z, xv.w};
    float rs[4];

#pragma unroll
    for (int l = 0; l < 4; ++l) {
        const float xx = xs[l];
        // interval search: t[i] <= x < t[i+1], i in [6,60]
        int j = (int)(xx * 55.0f);
        j = j < 0 ? 0 : (j > 54 ? 54 : j);
        int i = j + 6;
        if (i > 6 && xx < t[i]) --i;
        else if (i < 60 && xx >= t[i + 1]) ++i;

        const float l1 = xx - t[i];
        const float r1 = t[i + 1] - xx;
        const float l2 = xx - t[i - 1];
        const float r2 = t[i + 2] - xx;
        const float l3 = xx - t[i - 2];
        const float r3 = t[i + 3] - xx;

        // de Boor basis algorithm (A2.2), divisions replaced by LDS reciprocals.
        // degree 1
        float temp = rd11[i];          // N0(=1) * 1/(t[i+1]-t[i])
        float N0 = r1 * temp;
        float N1 = l1 * temp;
        // degree 2
        temp = N0 * rd21[i];
        N0 = r1 * temp;
        float saved = l2 * temp;
        temp = N1 * rd22[i];
        N1 = saved + r2 * temp;
        float N2 = l1 * temp;
        // degree 3
        temp = N0 * rd31[i];
        N0 = r1 * temp;
        saved = l3 * temp;
        temp = N1 * rd32[i];
        N1 = saved + r2 * temp;
        saved = l2 * temp;
        temp = N2 * rd33[i];
        N2 = saved + r3 * temp;
        const float N3 = l1 * temp;

        // nonzero basis rows are (i-3)..i of control_p
        const float* c = cp + (i - 3) * NF + f0 + l;
        rs[l] = N0 * c[0] + N1 * c[NF] + N2 * c[2 * NF] + N3 * c[3 * NF];
    }

    float4 ov;
    ov.x = rs[0] + bv.x;
    ov.y = rs[1] + bv.y;
    ov.z = rs[2] + bv.z;
    ov.w = rs[3] + bv.w;
    reinterpret_cast<float4*>(out)[gid] = ov;
}

extern "C" void kernel_launch(void* const* d_in, const int* in_sizes, int n_in,
                              void* d_out, int out_size, void* d_ws, size_t ws_size,
                              hipStream_t stream) {
    const float* x    = (const float*)d_in[0];   // (4096, 256)
    const float* cp   = (const float*)d_in[1];   // (64, 256)
    const float* bias = (const float*)d_in[2];   // (256,)
    float* out = (float*)d_out;

    const int total4 = out_size / 4;             // 262144 float4s
    const int block = 256;
    const int grid = (total4 + block - 1) / block;
    bspline_kernel<<<grid, block, 0, stream>>>(x, cp, bias, out, total4);
}

// Round 2
// 60.972 us; speedup vs baseline: 1.0955x; 1.0955x over previous
//
#include <hip/hip_runtime.h>

#define NF 256          // NUM_NEURONS
#define NK 64           // NUM_KNOTS (cp rows)
#define ROWS_PER_BLOCK 8

// out[b,f] = sum_{r=0..3} N_r(x[b,f]) * cp[i-3+r, f] + bias[f]
// where i = interval index (t[i] <= x < t[i+1]), i = j+6, j = floor(x*55).
//
// Knot vector t (68 entries) is piecewise linear in index k:
//   left pads:  t[k] = 0.0005*k - 0.0035          (k <= 5)
//   interior:   t[k] = (k-6)/55                   (6 <= k <= 61)
//   right pads: t[k] = 0.0005*(k-62) + 1.001      (k >= 62)
// and for the tap window k = j+4 .. j+9 each knot is exactly
// max(left-line, interior) or min(interior, right-line) — no tables needed.

__global__ __launch_bounds__(256, 2) void bspline_kernel(
    const float* __restrict__ x,
    const float* __restrict__ cp,     // (64, 256) row-major
    const float* __restrict__ bias,   // (256,)
    float* __restrict__ out)
{
    __shared__ float4 cpl4[NK * NF / 4];          // 64 KiB, natural (k,f) layout
    float* cpl = reinterpret_cast<float*>(cpl4);

    const int tid = threadIdx.x;

    // Stage all of control_p: coalesced dwordx4 loads -> ds_write_b128.
    {
        const float4* cp4 = reinterpret_cast<const float4*>(cp);
#pragma unroll
        for (int it = 0; it < NK * NF / 4 / 256; ++it)
            cpl4[tid + 256 * it] = cp4[tid + 256 * it];
    }

    const float bv = bias[tid];                   // f = tid for this thread
    __syncthreads();

    const int r0 = blockIdx.x * ROWS_PER_BLOCK;
    constexpr float inv55 = 1.0f / 55.0f;

#pragma unroll
    for (int j = 0; j < ROWS_PER_BLOCK; ++j) {
        const float xx = x[(r0 + j) * NF + tid];

        float jf = floorf(xx * 55.0f);
        jf = fminf(fmaxf(jf, 0.0f), 54.0f);       // defensive clamp (v_med3)
        const int ji = (int)jf;                   // interval i = ji + 6

        // knots t[i-2..i+3]; k = ji + {4..9}
        const float t_im2 = fmaxf(fmaf(jf, 5e-4f, -1.5e-3f), (jf - 2.0f) * inv55);
        const float t_im1 = fmaxf(fmaf(jf, 5e-4f, -1.0e-3f), (jf - 1.0f) * inv55);
        const float t_i   = jf * inv55;
        const float t_ip1 = (jf + 1.0f) * inv55;
        const float t_ip2 = fminf((jf + 2.0f) * inv55, fmaf(jf, 5e-4f, 0.974f));
        const float t_ip3 = fminf((jf + 3.0f) * inv55, fmaf(jf, 5e-4f, 0.9745f));

        const float l1 = xx - t_i,   r1 = t_ip1 - xx;
        const float l2 = xx - t_im1, r2 = t_ip2 - xx;
        const float l3 = xx - t_im2, r3 = t_ip3 - xx;

        // denominators as l+r sums; v_rcp_f32 (1 ulp) — threshold is 0.099
        const float rd11 = __builtin_amdgcn_rcpf(l1 + r1);
        const float rd21 = __builtin_amdgcn_rcpf(l2 + r1);
        const float rd22 = __builtin_amdgcn_rcpf(l1 + r2);
        const float rd31 = __builtin_amdgcn_rcpf(l3 + r1);
        const float rd32 = __builtin_amdgcn_rcpf(l2 + r2);
        const float rd33 = __builtin_amdgcn_rcpf(l1 + r3);

        // de Boor basis (A2.2), division-free
        float temp = rd11;
        float N0 = r1 * temp;
        float N1 = l1 * temp;
        temp = N0 * rd21; N0 = r1 * temp; float saved = l2 * temp;
        temp = N1 * rd22; N1 = fmaf(r2, temp, saved); float N2 = l1 * temp;
        temp = N0 * rd31; N0 = r1 * temp; saved = l3 * temp;
        temp = N1 * rd32; N1 = fmaf(r2, temp, saved); saved = l2 * temp;
        temp = N2 * rd33; N2 = fmaf(r3, temp, saved); const float N3 = l1 * temp;

        // taps: cp rows ji+3 .. ji+6, feature f=tid.
        // LDS bank = tid%32 -> 2-way aliasing only (free).
        const float* c = &cpl[(ji + 3) * NF + tid];
        float acc = fmaf(N0, c[0 * NF], bv);
        acc = fmaf(N1, c[1 * NF], acc);
        acc = fmaf(N2, c[2 * NF], acc);
        acc = fmaf(N3, c[3 * NF], acc);

        out[(r0 + j) * NF + tid] = acc;
    }
}

extern "C" void kernel_launch(void* const* d_in, const int* in_sizes, int n_in,
                              void* d_out, int out_size, void* d_ws, size_t ws_size,
                              hipStream_t stream) {
    const float* x    = (const float*)d_in[0];   // (4096, 256)
    const float* cp   = (const float*)d_in[1];   // (64, 256)
    const float* bias = (const float*)d_in[2];   // (256,)
    float* out = (float*)d_out;

    const int batch = in_sizes[0] / NF;          // 4096
    const int grid = batch / ROWS_PER_BLOCK;     // 512 blocks x 256 threads
    bspline_kernel<<<grid, 256, 0, stream>>>(x, cp, bias, out);
}

// Round 3
// 60.711 us; speedup vs baseline: 1.1002x; 1.0043x over previous
//
#include <hip/hip_runtime.h>

#define NF 256          // NUM_NEURONS
#define NK 64           // NUM_KNOTS (cp rows)
#define FPB 64          // features per block
#define RPB 32          // rows per block

// out[b,f] = sum_{r=0..3} N_r(x[b,f]) * cp[i-3+r, f] + bias[f]
// i = interval (t[i] <= x < t[i+1]) = ji + 6, ji = floor(x*55).
// Knot vector (68 entries) is piecewise linear in index k:
//   k<=5:      t = 0.0005k - 0.0035
//   6<=k<=61:  t = (k-6)/55
//   k>=62:     t = 0.0005(k-62) + 1.001
// For the 6-knot tap window each knot is exactly max(left-line, interior)
// or min(interior, right-line) — closed form, no tables.

__global__ __launch_bounds__(256, 2) void bspline_kernel(
    const float* __restrict__ x,
    const float* __restrict__ cp,     // (64, 256) row-major
    const float* __restrict__ bias,   // (256,)
    float* __restrict__ out)
{
    __shared__ float4 cpl4[NK * FPB / 4];         // 16 KiB: (k, ff) slab
    float* cpl = reinterpret_cast<float*>(cpl4);

    const int tid  = threadIdx.x;
    const int ff   = tid & (FPB - 1);             // feature offset in group
    const int rsub = tid >> 6;                    // 0..3 row sub-lane
    const int fg   = blockIdx.x & 3;              // feature group (0..3)
    const int rg   = blockIdx.x >> 2;             // row group
    const int f0   = fg * FPB;
    const int r0   = rg * RPB;

    // ---- prefetch x into registers (overlaps staging + barrier) ----
    const float* xp = x + (r0 + rsub) * NF + f0 + ff;
    float xv[8];
#pragma unroll
    for (int it = 0; it < 8; ++it)
        xv[it] = xp[it * 4 * NF];

    // ---- stage this block's 64-feature slab of cp ----
    {
        const float4* cp4 = reinterpret_cast<const float4*>(cp);
        const int fb4 = f0 >> 2;                  // float4 col base (features/4)
#pragma unroll
        for (int s = 0; s < 4; ++s) {
            const int idx = tid + 256 * s;        // 0..1023
            const int k   = idx >> 4;             // knot row 0..63
            const int c4  = idx & 15;             // float4 col in slab
            cpl4[idx] = cp4[k * (NF / 4) + fb4 + c4];
        }
    }
    const float bv = bias[f0 + ff];
    __syncthreads();

    constexpr float inv55 = 1.0f / 55.0f;

#pragma unroll
    for (int it = 0; it < 8; ++it) {
        const float xx = xv[it];

        float jf = floorf(xx * 55.0f);
        jf = fminf(fmaxf(jf, 0.0f), 54.0f);       // v_med3 clamp
        const int ji = (int)jf;

        // knots t[i-2..i+3]
        const float t_im2 = fmaxf(fmaf(jf, 5e-4f, -1.5e-3f), (jf - 2.0f) * inv55);
        const float t_im1 = fmaxf(fmaf(jf, 5e-4f, -1.0e-3f), (jf - 1.0f) * inv55);
        const float t_i   = jf * inv55;
        const float t_ip1 = (jf + 1.0f) * inv55;
        const float t_ip2 = fminf((jf + 2.0f) * inv55, fmaf(jf, 5e-4f, 0.974f));
        const float t_ip3 = fminf((jf + 3.0f) * inv55, fmaf(jf, 5e-4f, 0.9745f));

        const float l1 = xx - t_i,   r1 = t_ip1 - xx;
        const float l2 = xx - t_im1, r2 = t_ip2 - xx;
        const float l3 = xx - t_im2, r3 = t_ip3 - xx;

        const float rd11 = __builtin_amdgcn_rcpf(l1 + r1);
        const float rd21 = __builtin_amdgcn_rcpf(l2 + r1);
        const float rd22 = __builtin_amdgcn_rcpf(l1 + r2);
        const float rd31 = __builtin_amdgcn_rcpf(l3 + r1);
        const float rd32 = __builtin_amdgcn_rcpf(l2 + r2);
        const float rd33 = __builtin_amdgcn_rcpf(l1 + r3);

        // de Boor basis (A2.2), division-free
        float temp = rd11;
        float N0 = r1 * temp;
        float N1 = l1 * temp;
        temp = N0 * rd21; N0 = r1 * temp; float saved = l2 * temp;
        temp = N1 * rd22; N1 = fmaf(r2, temp, saved); float N2 = l1 * temp;
        temp = N0 * rd31; N0 = r1 * temp; saved = l3 * temp;
        temp = N1 * rd32; N1 = fmaf(r2, temp, saved); saved = l2 * temp;
        temp = N2 * rd33; N2 = fmaf(r3, temp, saved); const float N3 = l1 * temp;

        // LDS gather: rows ji+3..ji+6 of the slab; bank = lane&31 -> free
        const float* c = &cpl[(ji + 3) * FPB + ff];
        float acc = fmaf(N0, c[0 * FPB], bv);
        acc = fmaf(N1, c[1 * FPB], acc);
        acc = fmaf(N2, c[2 * FPB], acc);
        acc = fmaf(N3, c[3 * FPB], acc);

        out[(r0 + rsub + it * 4) * NF + f0 + ff] = acc;
    }
}

extern "C" void kernel_launch(void* const* d_in, const int* in_sizes, int n_in,
                              void* d_out, int out_size, void* d_ws, size_t ws_size,
                              hipStream_t stream) {
    const float* x    = (const float*)d_in[0];   // (4096, 256)
    const float* cp   = (const float*)d_in[1];   // (64, 256)
    const float* bias = (const float*)d_in[2];   // (256,)
    float* out = (float*)d_out;

    const int batch = in_sizes[0] / NF;          // 4096
    const int grid = (batch / RPB) * (NF / FPB); // 128 * 4 = 512 blocks
    bspline_kernel<<<grid, 256, 0, stream>>>(x, cp, bias, out);
}